// Round 19
// baseline (433.180 us; speedup 1.0000x reference)
//
#include <hip/hip_runtime.h>
#include <math.h>

// B=128, W=64, L=4096, MODES=32, N_LAYERS=4

typedef _Float16 half8 __attribute__((ext_vector_type(8)));  // 8 fp16 (4 VGPR)
typedef __fp16 fp16x2 __attribute__((ext_vector_type(2)));   // builtin cvt_pkrtz type
typedef __attribute__((ext_vector_type(4))) float fx4;       // MFMA f32 acc

// fast gelu: tanh/sigmoid form, exp2-folded. Max dev from exact-erf ~5e-4.
__device__ __forceinline__ float gelu_f(float x){
    float u = x*x;
    float a = x * fmaf(-0.1029443f, u, -2.3022083f);   // -2y*log2(e)
    float e = exp2f(a);                                 // e^{-2y}
    float r = __builtin_amdgcn_rcpf(1.0f + e);          // sigmoid(2y)
    return x * r;
}
__device__ __forceinline__ unsigned short f2h(float f){
    union { _Float16 h; unsigned short u; } c;
    c.h = (_Float16)f;
    return c.u;
}
__device__ __forceinline__ float h2f(unsigned short u){
    union { unsigned short u; _Float16 h; } c;
    c.u = u;
    return (float)c.h;
}
// packed f32x2 -> f16x2 (RTZ) in ONE v_cvt_pk_rtz_f16_f32
__device__ __forceinline__ unsigned int pkrtz(float a, float b){
    union { fp16x2 v; unsigned int u; } c;
    c.v = __builtin_amdgcn_cvt_pkrtz(a, b);
    return c.u;
}

// ---------------- workspace layout (float-slot offsets) ----------------
static const size_t OFF_XH     = 0;            // fp16 [128][64][4096]
static const size_t OFF_TABB   = 33554432;     // fp16 [64][4096]
static const size_t OFF_TABT   = 33685504;     // fp16 [4096][64] (x 1/64)
static const size_t OFF_MAH    = 33816576;     // fp16 [b][co][64]
static const size_t OFF_PWWH   = 34078720;
static const size_t OFF_W1H    = 34086912;
static const size_t OFF_COND   = 34091008;
static const size_t OFF_STATS  = 34099200;     // 16,384 (A)
static const size_t OFF_DFTP   = 34115584;     // 4,194,304
static const size_t OFF_X0     = 38309888;     // 524,288
static const size_t OFF_STATS2 = 38834176;     // 16,384 (B)
// end = 38,850,560 slots = 155.4 MB (< proven 157.4 MB footprint)

// ---------------- trig tables + weight fp16 conversion ----------------
__global__ void k_tab(unsigned short* __restrict__ tabB, unsigned short* __restrict__ tabT,
                      const float* __restrict__ pww, unsigned short* __restrict__ pwwh,
                      const float* __restrict__ pj1w, unsigned short* __restrict__ w1h){
    int t = blockIdx.x*256 + threadIdx.x;        // 262144
    if (t < 16384) pwwh[t] = f2h(pww[t]);
    if (t < 8192)  w1h[t]  = f2h(pj1w[t]);
    int m2 = t >> 12, n = t & 4095;
    int m = m2 & 31;
    int r = (m*n) & 4095;
    int r2 = (r >= 2048) ? (r - 4096) : r;       // fold to [-pi, pi)
    float a = (float)r2 * 1.5339807878856412e-3f;   // 2*pi/4096
    float v = (m2 >= 32) ? sinf(a) : cosf(a);
    tabB[(size_t)m2*4096 + n] = f2h(v);
    tabT[(size_t)n*64 + m2]   = f2h(v * 0.015625f);
}

// ---------------- conditioning MLP ----------------
__global__ __launch_bounds__(64) void k_cond(const float* __restrict__ instp,
        const float* __restrict__ w1, const float* __restrict__ b1,
        const float* __restrict__ w2, const float* __restrict__ b2,
        float* __restrict__ cond){
    int b = blockIdx.x, tid = threadIdx.x;
    __shared__ float ipl[8];
    __shared__ float tl[64];
    if (tid < 8) ipl[tid] = instp[b*8 + tid];
    __syncthreads();
    float s = b1[tid];
    #pragma unroll
    for (int k = 0; k < 8; ++k) s = fmaf(ipl[k], w1[k*64 + tid], s);
    tl[tid] = gelu_f(s);
    __syncthreads();
    float c = b2[tid];
    #pragma unroll 8
    for (int j = 0; j < 64; ++j) c = fmaf(tl[j], w2[j*64 + tid], c);
    cond[b*64 + tid] = c;
}

// ---------------- lift core: x0 = z @ lift_w + lb + cond (f32, 2 MB) ----------------
__global__ __launch_bounds__(256) void k_liftc(const float* __restrict__ z,
        const float* __restrict__ lw, const float* __restrict__ lb,
        const float* __restrict__ cond, float* __restrict__ x0){
    int b = blockIdx.x, q = blockIdx.y;
    int t = threadIdx.x;
    __shared__ float zl[128];
    if (t < 128) zl[t] = z[b*128 + t];
    __syncthreads();
    #pragma unroll
    for (int i = 0; i < 4; ++i){
        int e = q*1024 + i*256 + t;            // e = wc*64 + pos
        float s = lb[e];
        #pragma unroll 8
        for (int d = 0; d < 128; ++d)
            s = fmaf(zl[d], lw[(size_t)d*4096 + e], s);
        x0[(size_t)b*4096 + e] = s + cond[b*64 + (e >> 6)];
    }
}

// ---------------- prep: (interp | norm+gelu) -> x (LDS), fwd-DFT -> dftp --------
// MODE: 1 = norm+gelu from xh; 2 = inline linear-interp from x0 (layer 0).
template<int MODE>
__global__ __launch_bounds__(256) void k_prep(
        const unsigned short* __restrict__ xhp, const float* __restrict__ statsIn,
        const unsigned short* __restrict__ tabB, const float* __restrict__ x0,
        float* __restrict__ dftp)
{
    int b = blockIdx.x, ng = blockIdx.y;
    int t = threadIdx.x;
    int w = t >> 6, lane = t & 63;
    int lrow = lane & 15, g = lane >> 4;
    __shared__ __align__(16) unsigned short xl[2][4096];
    __shared__ float xs[(MODE == 2) ? 65*64 : 1];   // [ci][64+1 pad]
    int ci = t >> 2, nq = t & 3;
    float mu = 0.f, rs = 1.f;
    if (MODE == 1){
        float2 sr = *(const float2*)(statsIn + (size_t)(b*64+ci)*2);
        mu = sr.x * (1.f/4096.f);
        float var = fmaf(sr.y, 1.f/4096.f, -mu*mu);
        rs = rsqrtf(var + 1e-5f);
    }
    if (MODE == 2){
        const float* xb0 = x0 + (size_t)b*4096;
        #pragma unroll
        for (int i = 0; i < 16; ++i){
            int idx = i*256 + t;
            xs[(idx >> 6)*65 + (idx & 63)] = xb0[idx];
        }
        __syncthreads();
    }
    fx4 acc[4];
    #pragma unroll
    for (int i = 0; i < 4; ++i) acc[i] = (fx4){0.f,0.f,0.f,0.f};

    const unsigned short* hrow = xhp + ((size_t)(b*64+ci))*4096 + ng*512 + nq*16;

    uint4 cA, cB;
    if (MODE == 1){ cA = *(const uint4*)(hrow); cB = *(const uint4*)(hrow + 8); }
    for (int it = 0; it < 8; ++it){
        int n0 = ng*512 + it*64;
        char* xb = (char*)(&xl[it & 1][0]);
        uint4 nA, nB;
        if (MODE == 1 && it < 7){
            nA = *(const uint4*)(hrow + (it+1)*64);
            nB = *(const uint4*)(hrow + (it+1)*64 + 8);
        }
        unsigned int pk[8];
        if (MODE == 1){
            unsigned int hu[8] = {cA.x,cA.y,cA.z,cA.w,cB.x,cB.y,cB.z,cB.w};
            #pragma unroll
            for (int i = 0; i < 8; ++i){
                float f0 = h2f((unsigned short)(hu[i] & 0xFFFFu));
                float f1 = h2f((unsigned short)(hu[i] >> 16));
                f0 = gelu_f((f0 - mu)*rs);
                f1 = gelu_f((f1 - mu)*rs);
                pk[i] = pkrtz(f0, f1);
            }
        } else {
            const float* xr = xs + ci*65;
            #pragma unroll
            for (int i = 0; i < 8; ++i){
                float v[2];
                #pragma unroll
                for (int q = 0; q < 2; ++q){
                    int n = n0 + nq*16 + i*2 + q;
                    float src = (n + 0.5f)*0.015625f - 0.5f;
                    src = fminf(fmaxf(src, 0.0f), 63.0f);
                    int i0 = (int)src;
                    int i1 = (i0 + 1 > 63) ? 63 : (i0 + 1);
                    float wt = src - (float)i0;
                    v[q] = xr[i0] + wt*(xr[i1] - xr[i0]);
                }
                pk[i] = pkrtz(v[0], v[1]);
            }
        }
        unsigned int base = (unsigned int)ci*128 + (unsigned int)nq*32;
        unsigned int sw = (unsigned int)((ci & 7) << 4);
        *(uint4*)(xb + ((base +  0) ^ sw)) = make_uint4(pk[0],pk[1],pk[2],pk[3]);
        *(uint4*)(xb + ((base + 16) ^ sw)) = make_uint4(pk[4],pk[5],pk[6],pk[7]);
        __syncthreads();

        {   // forward DFT MFMAs
            int m0 = w*16;
            #pragma unroll
            for (int ks = 0; ks < 2; ++ks){
                int kk = ks*32 + g*8;
                half8 af = *(const half8*)(tabB + (size_t)(m0 + lrow)*4096 + n0 + kk);
                #pragma unroll
                for (int ct = 0; ct < 4; ++ct){
                    int row = ct*16 + lrow;
                    unsigned int ba = ((unsigned int)row*128 + (unsigned int)kk*2)
                                      ^ (unsigned int)((row & 7) << 4);
                    half8 bf = *(const half8*)(xb + ba);
                    acc[ct] = __builtin_amdgcn_mfma_f32_16x16x32_f16(af, bf, acc[ct], 0, 0, 0);
                }
            }
        }
        if (MODE == 1 && it < 7){ cA = nA; cB = nB; }
    }
    {   // dftp [b][ng][ci][m2], float4 stores
        int m0 = w*16;
        #pragma unroll
        for (int ct = 0; ct < 4; ++ct){
            float4 v = make_float4(acc[ct][0], acc[ct][1], acc[ct][2], acc[ct][3]);
            *(float4*)(dftp + ((size_t)(b*8+ng)*64 + ct*16 + lrow)*64 + m0 + g*4) = v;
        }
    }
}

// ---------------- spectral mix (fused dftred + stats-target zero) ----------------
// grid (128 b, 4 coq), 512 thr: (mq=t&3, ciq=(t>>2)&7, co_l=t>>5). 8-ci chains.
__global__ __launch_bounds__(512) void k_mix(const float* __restrict__ dftp,
        const float* __restrict__ specw, unsigned short* __restrict__ mah,
        float* __restrict__ statsZero, int l){
    int b = blockIdx.x, coq = blockIdx.y, t = threadIdx.x;
    __shared__ float xm[64*64];              // [ci][64]: r | i
    if (t < 128) statsZero[b*128 + t] = 0.f;
    const float* dp = dftp + (size_t)b*8*4096;
    #pragma unroll
    for (int i = 0; i < 2; ++i){
        int e = i*2048 + t*4;
        float4 s = make_float4(0.f,0.f,0.f,0.f);
        #pragma unroll
        for (int ng = 0; ng < 8; ++ng){
            float4 v = *(const float4*)(dp + (size_t)ng*4096 + e);
            s.x += v.x; s.y += v.y; s.z += v.z; s.w += v.w;
        }
        if (e & 32){ s.x = -s.x; s.y = -s.y; s.z = -s.z; s.w = -s.w; }
        *(float4*)(xm + e) = s;
    }
    __syncthreads();
    int mq = t & 3, ciq = (t >> 2) & 7, co_l = t >> 5;
    int co = coq*16 + co_l;
    float yr[8] = {0,0,0,0,0,0,0,0}, yi[8] = {0,0,0,0,0,0,0,0};
    const float* wbase = specw + (size_t)l*262144 + (size_t)co*64 + mq*16;
    #pragma unroll
    for (int cil = 0; cil < 8; ++cil){
        int ci = ciq*8 + cil;
        const float* wp = wbase + (size_t)ci*4096;
        float4 w0 = *(const float4*)(wp);
        float4 w1v = *(const float4*)(wp + 4);
        float4 w2v = *(const float4*)(wp + 8);
        float4 w3v = *(const float4*)(wp + 12);
        const float* xc = xm + ci*64 + mq*8;
        float4 r0 = *(const float4*)(xc);
        float4 r1 = *(const float4*)(xc + 4);
        float4 i0 = *(const float4*)(xc + 32);
        float4 i1 = *(const float4*)(xc + 36);
        float wr[8] = {w0.x,w0.z,w1v.x,w1v.z,w2v.x,w2v.z,w3v.x,w3v.z};
        float wi[8] = {w0.y,w0.w,w1v.y,w1v.w,w2v.y,w2v.w,w3v.y,w3v.w};
        float xr[8] = {r0.x,r0.y,r0.z,r0.w,r1.x,r1.y,r1.z,r1.w};
        float xi[8] = {i0.x,i0.y,i0.z,i0.w,i1.x,i1.y,i1.z,i1.w};
        #pragma unroll
        for (int mm = 0; mm < 8; ++mm){
            yr[mm] = fmaf(xr[mm], wr[mm], fmaf(-xi[mm], wi[mm], yr[mm]));
            yi[mm] = fmaf(xr[mm], wi[mm], fmaf( xi[mm], wr[mm], yi[mm]));
        }
    }
    #pragma unroll
    for (int mm = 0; mm < 8; ++mm){
        yr[mm] += __shfl_xor(yr[mm], 4); yr[mm] += __shfl_xor(yr[mm], 8);
        yr[mm] += __shfl_xor(yr[mm], 16);
        yi[mm] += __shfl_xor(yi[mm], 4); yi[mm] += __shfl_xor(yi[mm], 8);
        yi[mm] += __shfl_xor(yi[mm], 16);
    }
    if (ciq == 0){
        unsigned short* mb = mah + (size_t)(b*64 + co)*64;
        unsigned int pr[4], pi[4];
        #pragma unroll
        for (int p = 0; p < 4; ++p){
            int m0 = mq*8 + 2*p;
            float s0 = (m0 == 0) ? 0.015625f : 0.03125f;
            pr[p] = (unsigned int)f2h(s0*yr[2*p]) | ((unsigned int)f2h(0.03125f*yr[2*p+1]) << 16);
            pi[p] = (unsigned int)f2h(-0.03125f*yi[2*p]) | ((unsigned int)f2h(-0.03125f*yi[2*p+1]) << 16);
        }
        *(uint4*)(mb + mq*8)      = make_uint4(pr[0],pr[1],pr[2],pr[3]);
        *(uint4*)(mb + 32 + mq*8) = make_uint4(pi[0],pi[1],pi[2],pi[3]);
    }
}

// ---------------- pass3: x rebuilt from xh inline, pw+iDFT MFMA -> h (in place) ----
// grid (128 b, 16 ng of 256 n), 4 iters per block.
template<int MODE>
__global__ __launch_bounds__(256, 2) void k_pass3(
        const unsigned short* __restrict__ xhp, const float* __restrict__ statsIn,
        const float* __restrict__ x0, const unsigned short* __restrict__ tabT,
        const unsigned short* __restrict__ pwwh, const float* __restrict__ pwb,
        const unsigned short* __restrict__ mah, unsigned short* __restrict__ xh,
        float* __restrict__ statsOut, int lay)
{
    int b = blockIdx.x, ng = blockIdx.y;
    int t = threadIdx.x, w = t >> 6, lane = t & 63;
    int lrow = lane & 15, g = lane >> 4;
    __shared__ __align__(16) unsigned short xl1[4096];   // [ci][n] swizzled
    __shared__ __align__(16) unsigned short xl2[4096];   // [n][ci] swizzled
    __shared__ float xs[(MODE == 2) ? 65*64 : 1];
    __shared__ float sred[2][4][64];

    int ci = t >> 2, nq = t & 3;
    float mu = 0.f, rs = 1.f;
    if (MODE == 1){
        float2 sr = *(const float2*)(statsIn + (size_t)(b*64+ci)*2);
        mu = sr.x * (1.f/4096.f);
        float var = fmaf(sr.y, 1.f/4096.f, -mu*mu);
        rs = rsqrtf(var + 1e-5f);
    }
    if (MODE == 2){
        const float* xb0 = x0 + (size_t)b*4096;
        #pragma unroll
        for (int i = 0; i < 16; ++i){
            int idx = i*256 + t;
            xs[(idx >> 6)*65 + (idx & 63)] = xb0[idx];
        }
        __syncthreads();
    }
    half8 Bv[4][4];                          // [cot][ks], held
    #pragma unroll
    for (int cot = 0; cot < 4; ++cot){
        int co = cot*16 + lrow;
        #pragma unroll
        for (int ks = 0; ks < 4; ++ks){
            int k = ks*32 + g*8;
            const unsigned short* src = (k < 64)
                ? (pwwh + ((size_t)lay*64 + co)*64 + k)
                : (mah  + ((size_t)b*64 + co)*64 + (k - 64));
            Bv[cot][ks] = *(const half8*)src;
        }
    }
    float pb[4];
    #pragma unroll
    for (int cot = 0; cot < 4; ++cot) pb[cot] = pwb[lay*64 + cot*16 + lrow];
    float sS[4] = {0,0,0,0}, sQ[4] = {0,0,0,0};

    const unsigned short* hrow = xhp + ((size_t)(b*64+ci))*4096 + ng*256 + nq*16;
    uint4 cA, cB;
    if (MODE == 1){ cA = *(const uint4*)(hrow); cB = *(const uint4*)(hrow + 8); }

    for (int it = 0; it < 4; ++it){
        int n0 = ng*256 + it*64;
        uint4 nA, nB;
        if (MODE == 1 && it < 3){
            nA = *(const uint4*)(hrow + (it+1)*64);
            nB = *(const uint4*)(hrow + (it+1)*64 + 8);
        }
        unsigned int pk[8];
        if (MODE == 1){
            unsigned int hu[8] = {cA.x,cA.y,cA.z,cA.w,cB.x,cB.y,cB.z,cB.w};
            #pragma unroll
            for (int i = 0; i < 8; ++i){
                float f0 = h2f((unsigned short)(hu[i] & 0xFFFFu));
                float f1 = h2f((unsigned short)(hu[i] >> 16));
                f0 = gelu_f((f0 - mu)*rs);
                f1 = gelu_f((f1 - mu)*rs);
                pk[i] = pkrtz(f0, f1);
            }
        } else {
            const float* xr = xs + ci*65;
            #pragma unroll
            for (int i = 0; i < 8; ++i){
                float v[2];
                #pragma unroll
                for (int q = 0; q < 2; ++q){
                    int n = n0 + nq*16 + i*2 + q;
                    float src = (n + 0.5f)*0.015625f - 0.5f;
                    src = fminf(fmaxf(src, 0.0f), 63.0f);
                    int i0 = (int)src;
                    int i1 = (i0 + 1 > 63) ? 63 : (i0 + 1);
                    float wt = src - (float)i0;
                    v[q] = xr[i0] + wt*(xr[i1] - xr[i0]);
                }
                pk[i] = pkrtz(v[0], v[1]);
            }
        }
        unsigned int base = (unsigned int)ci*128 + (unsigned int)nq*32;
        unsigned int sw = (unsigned int)((ci & 7) << 4);
        *(uint4*)((char*)xl1 + ((base +  0) ^ sw)) = make_uint4(pk[0],pk[1],pk[2],pk[3]);
        *(uint4*)((char*)xl1 + ((base + 16) ^ sw)) = make_uint4(pk[4],pk[5],pk[6],pk[7]);
        __syncthreads();

        {   // transpose LDS1 [ci][n] -> LDS2 [n][ci] (both swizzled)
            int n = t & 63, coq = t >> 6;
            unsigned int opk[8];
            #pragma unroll
            for (int i = 0; i < 8; ++i){
                int r0 = coq*16 + 2*i, r1 = r0 + 1;
                unsigned int a0 = ((unsigned int)r0*128 + (unsigned int)n*2)
                                  ^ (unsigned int)((r0 & 7) << 4);
                unsigned int a1 = ((unsigned int)r1*128 + (unsigned int)n*2)
                                  ^ (unsigned int)((r1 & 7) << 4);
                unsigned short v0 = *(const unsigned short*)((const char*)xl1 + a0);
                unsigned short v1 = *(const unsigned short*)((const char*)xl1 + a1);
                opk[i] = (unsigned int)v0 | ((unsigned int)v1 << 16);
            }
            unsigned int b0 = (unsigned int)n*128 + (unsigned int)coq*32;
            unsigned int swn = (unsigned int)((n & 7) << 4);
            *(uint4*)((char*)xl2 + ((b0 +  0) ^ swn)) = make_uint4(opk[0],opk[1],opk[2],opk[3]);
            *(uint4*)((char*)xl2 + ((b0 + 16) ^ swn)) = make_uint4(opk[4],opk[5],opk[6],opk[7]);
        }
        __syncthreads();

        // MFMA: wave w owns n rows [w*16, w*16+16) of this 64-tile
        int nl = w*16 + lrow;
        unsigned int swa = (unsigned int)((nl & 7) << 4);
        half8 Af[4];
        Af[0] = *(const half8*)((const char*)xl2 + (((unsigned int)nl*128 +  0 + g*16) ^ swa));
        Af[1] = *(const half8*)((const char*)xl2 + (((unsigned int)nl*128 + 64 + g*16) ^ swa));
        {
            const unsigned short* tb = tabT + (size_t)(n0 + nl)*64 + g*8;
            Af[2] = *(const half8*)(tb);
            Af[3] = *(const half8*)(tb + 32);
        }
        fx4 acc[4];
        #pragma unroll
        for (int i = 0; i < 4; ++i) acc[i] = (fx4){0.f,0.f,0.f,0.f};
        #pragma unroll
        for (int ks = 0; ks < 4; ++ks)
            #pragma unroll
            for (int cot = 0; cot < 4; ++cot)
                acc[cot] = __builtin_amdgcn_mfma_f32_16x16x32_f16(Af[ks], Bv[cot][ks], acc[cot], 0, 0, 0);

        // epilogue: h = acc + bias; packed uint2 store; stats accumulate
        #pragma unroll
        for (int cot = 0; cot < 4; ++cot){
            int co = cot*16 + lrow;
            unsigned short* hr = xh + ((size_t)(b*64+co))*4096;
            float h0 = acc[cot][0] + pb[cot];
            float h1 = acc[cot][1] + pb[cot];
            float h2 = acc[cot][2] + pb[cot];
            float h3 = acc[cot][3] + pb[cot];
            uint2 pk2;
            pk2.x = pkrtz(h0, h1);
            pk2.y = pkrtz(h2, h3);
            *(uint2*)(hr + n0 + w*16 + g*4) = pk2;
            sS[cot] += (h0 + h1) + (h2 + h3);
            float q = h0*h0;
            q = fmaf(h1, h1, q); q = fmaf(h2, h2, q); q = fmaf(h3, h3, q);
            sQ[cot] += q;
        }
        if (MODE == 1 && it < 3){ cA = nA; cB = nB; }
    }
    #pragma unroll
    for (int cot = 0; cot < 4; ++cot){
        float s = sS[cot], q = sQ[cot];
        s += __shfl_xor(s, 16); q += __shfl_xor(q, 16);
        s += __shfl_xor(s, 32); q += __shfl_xor(q, 32);
        if (g == 0){
            sred[0][w][cot*16 + lrow] = s;
            sred[1][w][cot*16 + lrow] = q;
        }
    }
    __syncthreads();
    if (t < 64){
        float S = 0.f, Q = 0.f;
        #pragma unroll
        for (int ww = 0; ww < 4; ++ww){ S += sred[0][ww][t]; Q += sred[1][ww][t]; }
        atomicAdd(statsOut + (size_t)(b*64+t)*2,     S);
        atomicAdd(statsOut + (size_t)(b*64+t)*2 + 1, Q);
    }
}

// ---------------- fused norm+gelu+projection head (LDS2 transpose, vector B) -----
// grid (128 b, 16 ng of 256 n), 4 iters per block.
__global__ __launch_bounds__(256) void k_proj2(
        const unsigned short* __restrict__ xhp, const float* __restrict__ statsIn,
        const unsigned short* __restrict__ w1h, const float* __restrict__ b1,
        const float* __restrict__ w2, const float* __restrict__ b2,
        float* __restrict__ out)
{
    int b = blockIdx.x, ng = blockIdx.y;
    int t = threadIdx.x, w = t >> 6, lane = t & 63;
    int lrow = lane & 15, g = lane >> 4;
    int o2h = w & 1, nhalf = w >> 1;
    __shared__ __align__(16) unsigned short xl1[4096];
    __shared__ __align__(16) unsigned short xl2[4096];
    __shared__ float sred[2][2][2][2][16];   // [buf][nhalf][nt][o2h][lrow]

    int ci = t >> 2, nq = t & 3;
    float2 sr = *(const float2*)(statsIn + (size_t)(b*64+ci)*2);
    float mu = sr.x * (1.f/4096.f);
    float var = fmaf(sr.y, 1.f/4096.f, -mu*mu);
    float rs = rsqrtf(var + 1e-5f);
    const unsigned short* hrow = xhp + ((size_t)(b*64+ci))*4096 + ng*256 + nq*16;

    half8 A[4][2];
    #pragma unroll
    for (int ot = 0; ot < 4; ++ot)
        #pragma unroll
        for (int ks = 0; ks < 2; ++ks)
            A[ot][ks] = *(const half8*)(w1h + (size_t)(o2h*64 + ot*16 + lrow)*64 + ks*32 + g*8);
    float bb[16], wv[16];
    #pragma unroll
    for (int ot = 0; ot < 4; ++ot)
        #pragma unroll
        for (int j = 0; j < 4; ++j){
            int o2 = o2h*64 + ot*16 + g*4 + j;
            bb[ot*4+j] = b1[o2];
            wv[ot*4+j] = w2[o2];
        }
    float bias2 = b2[0];

    uint4 cA = *(const uint4*)(hrow);
    uint4 cB = *(const uint4*)(hrow + 8);
    for (int it = 0; it < 4; ++it){
        uint4 nA, nB;
        if (it < 3){
            nA = *(const uint4*)(hrow + (it+1)*64);
            nB = *(const uint4*)(hrow + (it+1)*64 + 8);
        }
        unsigned int pk[8];
        {
            unsigned int hu[8] = {cA.x,cA.y,cA.z,cA.w,cB.x,cB.y,cB.z,cB.w};
            #pragma unroll
            for (int i = 0; i < 8; ++i){
                float f0 = h2f((unsigned short)(hu[i] & 0xFFFFu));
                float f1 = h2f((unsigned short)(hu[i] >> 16));
                f0 = gelu_f((f0 - mu)*rs);
                f1 = gelu_f((f1 - mu)*rs);
                pk[i] = pkrtz(f0, f1);
            }
        }
        unsigned int base = (unsigned int)ci*128 + (unsigned int)nq*32;
        unsigned int sw = (unsigned int)((ci & 7) << 4);
        *(uint4*)((char*)xl1 + ((base +  0) ^ sw)) = make_uint4(pk[0],pk[1],pk[2],pk[3]);
        *(uint4*)((char*)xl1 + ((base + 16) ^ sw)) = make_uint4(pk[4],pk[5],pk[6],pk[7]);
        __syncthreads();

        {   // transpose LDS1 -> LDS2
            int n = t & 63, coq = t >> 6;
            unsigned int opk[8];
            #pragma unroll
            for (int i = 0; i < 8; ++i){
                int r0 = coq*16 + 2*i, r1 = r0 + 1;
                unsigned int a0 = ((unsigned int)r0*128 + (unsigned int)n*2)
                                  ^ (unsigned int)((r0 & 7) << 4);
                unsigned int a1 = ((unsigned int)r1*128 + (unsigned int)n*2)
                                  ^ (unsigned int)((r1 & 7) << 4);
                unsigned short v0 = *(const unsigned short*)((const char*)xl1 + a0);
                unsigned short v1 = *(const unsigned short*)((const char*)xl1 + a1);
                opk[i] = (unsigned int)v0 | ((unsigned int)v1 << 16);
            }
            unsigned int b0 = (unsigned int)n*128 + (unsigned int)coq*32;
            unsigned int swn = (unsigned int)((n & 7) << 4);
            *(uint4*)((char*)xl2 + ((b0 +  0) ^ swn)) = make_uint4(opk[0],opk[1],opk[2],opk[3]);
            *(uint4*)((char*)xl2 + ((b0 + 16) ^ swn)) = make_uint4(opk[4],opk[5],opk[6],opk[7]);
        }
        __syncthreads();

        // out-store for previous iter
        if (it > 0 && t < 64){
            int nh = t >> 5, rem = t & 31, ntf = rem >> 4, cl = rem & 15;
            out[(size_t)b*4096 + ng*256 + (it-1)*64 + t] =
                sred[(it-1)&1][nh][ntf][0][cl] + sred[(it-1)&1][nh][ntf][1][cl] + bias2;
        }

        // MFMA: vector B-frags from LDS2
        #pragma unroll
        for (int nt = 0; nt < 2; ++nt){
            int n_l = nhalf*32 + nt*16 + lrow;
            unsigned int swa = (unsigned int)((n_l & 7) << 4);
            half8 Bf[2];
            Bf[0] = *(const half8*)((const char*)xl2 + (((unsigned int)n_l*128 +  0 + g*16) ^ swa));
            Bf[1] = *(const half8*)((const char*)xl2 + (((unsigned int)n_l*128 + 64 + g*16) ^ swa));
            fx4 acc[4];
            #pragma unroll
            for (int i = 0; i < 4; ++i) acc[i] = (fx4){0.f,0.f,0.f,0.f};
            #pragma unroll
            for (int ks = 0; ks < 2; ++ks)
                #pragma unroll
                for (int ot = 0; ot < 4; ++ot)
                    acc[ot] = __builtin_amdgcn_mfma_f32_16x16x32_f16(A[ot][ks], Bf[ks], acc[ot], 0, 0, 0);
            float p = 0.f;
            #pragma unroll
            for (int ot = 0; ot < 4; ++ot)
                #pragma unroll
                for (int j = 0; j < 4; ++j)
                    p = fmaf(wv[ot*4+j], gelu_f(acc[ot][j] + bb[ot*4+j]), p);
            p += __shfl_xor(p, 16); p += __shfl_xor(p, 32);
            if (lane < 16) sred[it & 1][nhalf][nt][o2h][lane] = p;
        }
        if (it < 3){ cA = nA; cB = nB; }
    }
    __syncthreads();
    if (t < 64){
        int nh = t >> 5, rem = t & 31, ntf = rem >> 4, cl = rem & 15;
        out[(size_t)b*4096 + ng*256 + 3*64 + t] =
            sred[1][nh][ntf][0][cl] + sred[1][nh][ntf][1][cl] + bias2;
    }
}

// ---------------- launch ----------------
extern "C" void kernel_launch(void* const* d_in, const int* in_sizes, int n_in,
                              void* d_out, int out_size, void* d_ws, size_t ws_size,
                              hipStream_t stream) {
    (void)in_sizes; (void)n_in; (void)out_size; (void)ws_size;
    const float* z      = (const float*)d_in[0];
    const float* instp  = (const float*)d_in[1];
    const float* lift_w = (const float*)d_in[2];
    const float* lift_b = (const float*)d_in[3];
    const float* iw1    = (const float*)d_in[4];
    const float* ib1    = (const float*)d_in[5];
    const float* iw2    = (const float*)d_in[6];
    const float* ib2    = (const float*)d_in[7];
    const float* specw  = (const float*)d_in[8];
    const float* pww    = (const float*)d_in[9];
    const float* pwb    = (const float*)d_in[10];
    const float* pj1w   = (const float*)d_in[11];
    const float* pj1b   = (const float*)d_in[12];
    const float* pj2w   = (const float*)d_in[13];
    const float* pj2b   = (const float*)d_in[14];

    float* ws = (float*)d_ws;
    unsigned short* xh    = (unsigned short*)(ws + OFF_XH);
    unsigned short* tabB  = (unsigned short*)(ws + OFF_TABB);
    unsigned short* tabT  = (unsigned short*)(ws + OFF_TABT);
    unsigned short* mah   = (unsigned short*)(ws + OFF_MAH);
    unsigned short* pwwh  = (unsigned short*)(ws + OFF_PWWH);
    unsigned short* w1h   = (unsigned short*)(ws + OFF_W1H);
    float* cond   = ws + OFF_COND;
    float* dftp   = ws + OFF_DFTP;
    float* x0     = ws + OFF_X0;
    float* sbuf[2] = { ws + OFF_STATS, ws + OFF_STATS2 };
    float* out    = (float*)d_out;

    k_tab  <<<dim3(1024),  dim3(256), 0, stream>>>(tabB, tabT, pww, pwwh, pj1w, w1h);
    k_cond <<<dim3(128),   dim3(64),  0, stream>>>(instp, iw1, ib1, iw2, ib2, cond);
    k_liftc<<<dim3(128,4), dim3(256), 0, stream>>>(z, lift_w, lift_b, cond, x0);

    for (int l = 0; l < 4; ++l){
        float* sIn  = sbuf[l & 1];
        float* sOut = sbuf[(l + 1) & 1];
        if (l == 0)
            k_prep<2><<<dim3(128,8), dim3(256), 0, stream>>>(xh, sIn, tabB, x0, dftp);
        else
            k_prep<1><<<dim3(128,8), dim3(256), 0, stream>>>(xh, sIn, tabB, x0, dftp);
        k_mix<<<dim3(128,4), dim3(512), 0, stream>>>(dftp, specw, mah, sOut, l);
        if (l == 0)
            k_pass3<2><<<dim3(128,16), dim3(256), 0, stream>>>(xh, sIn, x0, tabT, pwwh, pwb, mah, xh, sOut, l);
        else
            k_pass3<1><<<dim3(128,16), dim3(256), 0, stream>>>(xh, sIn, x0, tabT, pwwh, pwb, mah, xh, sOut, l);
    }
    k_proj2<<<dim3(128,16), dim3(256), 0, stream>>>(xh, sbuf[0], w1h, pj1b, pj2w, pj2b, out);
}

// Round 20
// 417.032 us; speedup vs baseline: 1.0387x; 1.0387x over previous
//
#include <hip/hip_runtime.h>
#include <math.h>

// B=128, W=64, L=4096, MODES=32, N_LAYERS=4

typedef _Float16 half8 __attribute__((ext_vector_type(8)));  // 8 fp16 (4 VGPR)
typedef __attribute__((ext_vector_type(4))) float fx4;       // MFMA f32 acc

// fast gelu: tanh/sigmoid form, exp2-folded. Max dev from exact-erf ~5e-4.
__device__ __forceinline__ float gelu_f(float x){
    float u = x*x;
    float a = x * fmaf(-0.1029443f, u, -2.3022083f);   // -2y*log2(e)
    float e = exp2f(a);                                 // e^{-2y}
    float r = __builtin_amdgcn_rcpf(1.0f + e);          // sigmoid(2y)
    return x * r;
}
__device__ __forceinline__ unsigned short f2h(float f){
    union { _Float16 h; unsigned short u; } c;
    c.h = (_Float16)f;
    return c.u;
}
__device__ __forceinline__ float h2f(unsigned short u){
    union { unsigned short u; _Float16 h; } c;
    c.u = u;
    return (float)c.h;
}

// ---------------- workspace layout (float-slot offsets) ----------------
static const size_t OFF_XH     = 0;            // fp16 [128][64][4096]
static const size_t OFF_TABB   = 33554432;     // fp16 [64][4096]
static const size_t OFF_TABT   = 33685504;     // fp16 [4096][64] (x 1/64)
static const size_t OFF_MAH    = 33816576;     // fp16 [b][co][64]
static const size_t OFF_PWWH   = 34078720;
static const size_t OFF_W1H    = 34086912;
static const size_t OFF_COND   = 34091008;
static const size_t OFF_STATS  = 34099200;     // 16,384 (A)
static const size_t OFF_DFTP   = 34115584;     // 4,194,304
static const size_t OFF_X0     = 38309888;     // 524,288
static const size_t OFF_STATS2 = 38834176;     // 16,384 (B)
// end = 38,850,560 slots = 155.4 MB (< proven 157.4 MB footprint)

// ---------------- trig tables + weight fp16 conversion ----------------
__global__ void k_tab(unsigned short* __restrict__ tabB, unsigned short* __restrict__ tabT,
                      const float* __restrict__ pww, unsigned short* __restrict__ pwwh,
                      const float* __restrict__ pj1w, unsigned short* __restrict__ w1h){
    int t = blockIdx.x*256 + threadIdx.x;        // 262144
    if (t < 16384) pwwh[t] = f2h(pww[t]);
    if (t < 8192)  w1h[t]  = f2h(pj1w[t]);
    int m2 = t >> 12, n = t & 4095;
    int m = m2 & 31;
    int r = (m*n) & 4095;
    int r2 = (r >= 2048) ? (r - 4096) : r;       // fold to [-pi, pi)
    float a = (float)r2 * 1.5339807878856412e-3f;   // 2*pi/4096
    float v = (m2 >= 32) ? sinf(a) : cosf(a);
    tabB[(size_t)m2*4096 + n] = f2h(v);
    tabT[(size_t)n*64 + m2]   = f2h(v * 0.015625f);
}

// ---------------- conditioning MLP ----------------
__global__ __launch_bounds__(64) void k_cond(const float* __restrict__ instp,
        const float* __restrict__ w1, const float* __restrict__ b1,
        const float* __restrict__ w2, const float* __restrict__ b2,
        float* __restrict__ cond){
    int b = blockIdx.x, tid = threadIdx.x;
    __shared__ float ipl[8];
    __shared__ float tl[64];
    if (tid < 8) ipl[tid] = instp[b*8 + tid];
    __syncthreads();
    float s = b1[tid];
    #pragma unroll
    for (int k = 0; k < 8; ++k) s = fmaf(ipl[k], w1[k*64 + tid], s);
    tl[tid] = gelu_f(s);
    __syncthreads();
    float c = b2[tid];
    #pragma unroll 8
    for (int j = 0; j < 64; ++j) c = fmaf(tl[j], w2[j*64 + tid], c);
    cond[b*64 + tid] = c;
}

// ---------------- lift core: x0 = z @ lift_w + lb + cond (f32, 2 MB) ----------------
__global__ __launch_bounds__(256) void k_liftc(const float* __restrict__ z,
        const float* __restrict__ lw, const float* __restrict__ lb,
        const float* __restrict__ cond, float* __restrict__ x0){
    int b = blockIdx.x, q = blockIdx.y;
    int t = threadIdx.x;
    __shared__ float zl[128];
    if (t < 128) zl[t] = z[b*128 + t];
    __syncthreads();
    #pragma unroll
    for (int i = 0; i < 4; ++i){
        int e = q*1024 + i*256 + t;            // e = wc*64 + pos
        float s = lb[e];
        #pragma unroll 8
        for (int d = 0; d < 128; ++d)
            s = fmaf(zl[d], lw[(size_t)d*4096 + e], s);
        x0[(size_t)b*4096 + e] = s + cond[b*64 + (e >> 6)];
    }
}

// ---------------- prep: (interp | norm+gelu) -> x (LDS), fwd-DFT -> dftp --------
// MODE: 1 = norm+gelu from xh; 2 = inline linear-interp from x0 (layer 0).
template<int MODE>
__global__ __launch_bounds__(256) void k_prep(
        const unsigned short* __restrict__ xhp, const float* __restrict__ statsIn,
        const unsigned short* __restrict__ tabB, const float* __restrict__ x0,
        float* __restrict__ dftp)
{
    int b = blockIdx.x, ng = blockIdx.y;
    int t = threadIdx.x;
    int w = t >> 6, lane = t & 63;
    int lrow = lane & 15, g = lane >> 4;
    __shared__ __align__(16) unsigned short xl[2][4096];
    __shared__ float xs[(MODE == 2) ? 65*64 : 1];   // [ci][64+1 pad]
    int ci = t >> 2, nq = t & 3;
    float mu = 0.f, rs = 1.f;
    if (MODE == 1){
        float2 sr = *(const float2*)(statsIn + (size_t)(b*64+ci)*2);
        mu = sr.x * (1.f/4096.f);
        float var = fmaf(sr.y, 1.f/4096.f, -mu*mu);
        rs = rsqrtf(var + 1e-5f);
    }
    if (MODE == 2){
        const float* xb0 = x0 + (size_t)b*4096;
        #pragma unroll
        for (int i = 0; i < 16; ++i){
            int idx = i*256 + t;
            xs[(idx >> 6)*65 + (idx & 63)] = xb0[idx];
        }
        __syncthreads();
    }
    fx4 acc[4];
    #pragma unroll
    for (int i = 0; i < 4; ++i) acc[i] = (fx4){0.f,0.f,0.f,0.f};

    const unsigned short* hrow = xhp + ((size_t)(b*64+ci))*4096 + ng*512 + nq*16;

    uint4 cA, cB;
    if (MODE == 1){ cA = *(const uint4*)(hrow); cB = *(const uint4*)(hrow + 8); }
    for (int it = 0; it < 8; ++it){
        int n0 = ng*512 + it*64;
        char* xb = (char*)(&xl[it & 1][0]);
        uint4 nA, nB;
        if (MODE == 1 && it < 7){
            nA = *(const uint4*)(hrow + (it+1)*64);
            nB = *(const uint4*)(hrow + (it+1)*64 + 8);
        }
        unsigned int pk[8];
        if (MODE == 1){
            unsigned int hu[8] = {cA.x,cA.y,cA.z,cA.w,cB.x,cB.y,cB.z,cB.w};
            #pragma unroll
            for (int i = 0; i < 8; ++i){
                float f0 = h2f((unsigned short)(hu[i] & 0xFFFFu));
                float f1 = h2f((unsigned short)(hu[i] >> 16));
                f0 = gelu_f((f0 - mu)*rs);
                f1 = gelu_f((f1 - mu)*rs);
                pk[i] = (unsigned int)f2h(f0) | ((unsigned int)f2h(f1) << 16);
            }
        } else {
            const float* xr = xs + ci*65;
            #pragma unroll
            for (int i = 0; i < 8; ++i){
                float v[2];
                #pragma unroll
                for (int q = 0; q < 2; ++q){
                    int n = n0 + nq*16 + i*2 + q;
                    float src = (n + 0.5f)*0.015625f - 0.5f;
                    src = fminf(fmaxf(src, 0.0f), 63.0f);
                    int i0 = (int)src;
                    int i1 = (i0 + 1 > 63) ? 63 : (i0 + 1);
                    float wt = src - (float)i0;
                    v[q] = xr[i0] + wt*(xr[i1] - xr[i0]);
                }
                pk[i] = (unsigned int)f2h(v[0]) | ((unsigned int)f2h(v[1]) << 16);
            }
        }
        unsigned int base = (unsigned int)ci*128 + (unsigned int)nq*32;
        unsigned int sw = (unsigned int)((ci & 7) << 4);
        *(uint4*)(xb + ((base +  0) ^ sw)) = make_uint4(pk[0],pk[1],pk[2],pk[3]);
        *(uint4*)(xb + ((base + 16) ^ sw)) = make_uint4(pk[4],pk[5],pk[6],pk[7]);
        __syncthreads();

        {   // forward DFT MFMAs
            int m0 = w*16;
            #pragma unroll
            for (int ks = 0; ks < 2; ++ks){
                int kk = ks*32 + g*8;
                half8 af = *(const half8*)(tabB + (size_t)(m0 + lrow)*4096 + n0 + kk);
                #pragma unroll
                for (int ct = 0; ct < 4; ++ct){
                    int row = ct*16 + lrow;
                    unsigned int ba = ((unsigned int)row*128 + (unsigned int)kk*2)
                                      ^ (unsigned int)((row & 7) << 4);
                    half8 bf = *(const half8*)(xb + ba);
                    acc[ct] = __builtin_amdgcn_mfma_f32_16x16x32_f16(af, bf, acc[ct], 0, 0, 0);
                }
            }
        }
        if (MODE == 1 && it < 7){ cA = nA; cB = nB; }
    }
    {   // dftp [b][ng][ci][m2], float4 stores
        int m0 = w*16;
        #pragma unroll
        for (int ct = 0; ct < 4; ++ct){
            float4 v = make_float4(acc[ct][0], acc[ct][1], acc[ct][2], acc[ct][3]);
            *(float4*)(dftp + ((size_t)(b*8+ng)*64 + ct*16 + lrow)*64 + m0 + g*4) = v;
        }
    }
}

// ---------------- spectral mix (fused dftred + stats-target zero), co-split -------
__global__ __launch_bounds__(256) void k_mix(const float* __restrict__ dftp,
        const float* __restrict__ specw, unsigned short* __restrict__ mah,
        float* __restrict__ statsZero, int l){
    int b = blockIdx.x, coq = blockIdx.y, t = threadIdx.x;
    __shared__ float xm[64*64];              // [ci][64]: r | i
    if (t < 128) statsZero[b*128 + t] = 0.f;
    const float* dp = dftp + (size_t)b*8*4096;
    #pragma unroll
    for (int i = 0; i < 4; ++i){
        int e = i*1024 + t*4;
        float4 s = make_float4(0.f,0.f,0.f,0.f);
        #pragma unroll
        for (int ng = 0; ng < 8; ++ng){
            float4 v = *(const float4*)(dp + (size_t)ng*4096 + e);
            s.x += v.x; s.y += v.y; s.z += v.z; s.w += v.w;
        }
        if (e & 32){ s.x = -s.x; s.y = -s.y; s.z = -s.z; s.w = -s.w; }
        *(float4*)(xm + e) = s;
    }
    __syncthreads();
    int mq = t & 3, ciq = (t >> 2) & 3, co_l = t >> 4;
    int co = coq*16 + co_l;
    float yr[8] = {0,0,0,0,0,0,0,0}, yi[8] = {0,0,0,0,0,0,0,0};
    const float* wbase = specw + (size_t)l*262144 + (size_t)co*64 + mq*16;
    #pragma unroll 4
    for (int cil = 0; cil < 16; ++cil){
        int ci = ciq*16 + cil;
        const float* wp = wbase + (size_t)ci*4096;
        float4 w0 = *(const float4*)(wp);
        float4 w1v = *(const float4*)(wp + 4);
        float4 w2v = *(const float4*)(wp + 8);
        float4 w3v = *(const float4*)(wp + 12);
        const float* xc = xm + ci*64 + mq*8;
        float4 r0 = *(const float4*)(xc);
        float4 r1 = *(const float4*)(xc + 4);
        float4 i0 = *(const float4*)(xc + 32);
        float4 i1 = *(const float4*)(xc + 36);
        float wr[8] = {w0.x,w0.z,w1v.x,w1v.z,w2v.x,w2v.z,w3v.x,w3v.z};
        float wi[8] = {w0.y,w0.w,w1v.y,w1v.w,w2v.y,w2v.w,w3v.y,w3v.w};
        float xr[8] = {r0.x,r0.y,r0.z,r0.w,r1.x,r1.y,r1.z,r1.w};
        float xi[8] = {i0.x,i0.y,i0.z,i0.w,i1.x,i1.y,i1.z,i1.w};
        #pragma unroll
        for (int mm = 0; mm < 8; ++mm){
            yr[mm] = fmaf(xr[mm], wr[mm], fmaf(-xi[mm], wi[mm], yr[mm]));
            yi[mm] = fmaf(xr[mm], wi[mm], fmaf( xi[mm], wr[mm], yi[mm]));
        }
    }
    #pragma unroll
    for (int mm = 0; mm < 8; ++mm){
        yr[mm] += __shfl_xor(yr[mm], 4); yr[mm] += __shfl_xor(yr[mm], 8);
        yi[mm] += __shfl_xor(yi[mm], 4); yi[mm] += __shfl_xor(yi[mm], 8);
    }
    if (ciq == 0){
        unsigned short* mb = mah + (size_t)(b*64 + co)*64;
        unsigned int pr[4], pi[4];
        #pragma unroll
        for (int p = 0; p < 4; ++p){
            int m0 = mq*8 + 2*p;
            float s0 = (m0 == 0) ? 0.015625f : 0.03125f;
            pr[p] = (unsigned int)f2h(s0*yr[2*p]) | ((unsigned int)f2h(0.03125f*yr[2*p+1]) << 16);
            pi[p] = (unsigned int)f2h(-0.03125f*yi[2*p]) | ((unsigned int)f2h(-0.03125f*yi[2*p+1]) << 16);
        }
        *(uint4*)(mb + mq*8)      = make_uint4(pr[0],pr[1],pr[2],pr[3]);
        *(uint4*)(mb + 32 + mq*8) = make_uint4(pi[0],pi[1],pi[2],pi[3]);
    }
}

// ---------------- pass3: x rebuilt from xh inline, pw+iDFT MFMA -> h (in place) ----
// grid (128 b, 16 ng of 256 n), 4 iters per block.
template<int MODE>
__global__ __launch_bounds__(256, 2) void k_pass3(
        const unsigned short* __restrict__ xhp, const float* __restrict__ statsIn,
        const float* __restrict__ x0, const unsigned short* __restrict__ tabT,
        const unsigned short* __restrict__ pwwh, const float* __restrict__ pwb,
        const unsigned short* __restrict__ mah, unsigned short* __restrict__ xh,
        float* __restrict__ statsOut, int lay)
{
    int b = blockIdx.x, ng = blockIdx.y;
    int t = threadIdx.x, w = t >> 6, lane = t & 63;
    int lrow = lane & 15, g = lane >> 4;
    __shared__ __align__(16) unsigned short xl1[4096];   // [ci][n] swizzled
    __shared__ __align__(16) unsigned short xl2[4096];   // [n][ci] swizzled
    __shared__ float xs[(MODE == 2) ? 65*64 : 1];
    __shared__ float sred[2][4][64];

    int ci = t >> 2, nq = t & 3;
    float mu = 0.f, rs = 1.f;
    if (MODE == 1){
        float2 sr = *(const float2*)(statsIn + (size_t)(b*64+ci)*2);
        mu = sr.x * (1.f/4096.f);
        float var = fmaf(sr.y, 1.f/4096.f, -mu*mu);
        rs = rsqrtf(var + 1e-5f);
    }
    if (MODE == 2){
        const float* xb0 = x0 + (size_t)b*4096;
        #pragma unroll
        for (int i = 0; i < 16; ++i){
            int idx = i*256 + t;
            xs[(idx >> 6)*65 + (idx & 63)] = xb0[idx];
        }
        __syncthreads();
    }
    half8 Bv[4][4];                          // [cot][ks], held
    #pragma unroll
    for (int cot = 0; cot < 4; ++cot){
        int co = cot*16 + lrow;
        #pragma unroll
        for (int ks = 0; ks < 4; ++ks){
            int k = ks*32 + g*8;
            const unsigned short* src = (k < 64)
                ? (pwwh + ((size_t)lay*64 + co)*64 + k)
                : (mah  + ((size_t)b*64 + co)*64 + (k - 64));
            Bv[cot][ks] = *(const half8*)src;
        }
    }
    float pb[4];
    #pragma unroll
    for (int cot = 0; cot < 4; ++cot) pb[cot] = pwb[lay*64 + cot*16 + lrow];
    float sS[4] = {0,0,0,0}, sQ[4] = {0,0,0,0};

    const unsigned short* hrow = xhp + ((size_t)(b*64+ci))*4096 + ng*256 + nq*16;
    uint4 cA, cB;
    if (MODE == 1){ cA = *(const uint4*)(hrow); cB = *(const uint4*)(hrow + 8); }

    for (int it = 0; it < 4; ++it){
        int n0 = ng*256 + it*64;
        uint4 nA, nB;
        if (MODE == 1 && it < 3){
            nA = *(const uint4*)(hrow + (it+1)*64);
            nB = *(const uint4*)(hrow + (it+1)*64 + 8);
        }
        unsigned int pk[8];
        if (MODE == 1){
            unsigned int hu[8] = {cA.x,cA.y,cA.z,cA.w,cB.x,cB.y,cB.z,cB.w};
            #pragma unroll
            for (int i = 0; i < 8; ++i){
                float f0 = h2f((unsigned short)(hu[i] & 0xFFFFu));
                float f1 = h2f((unsigned short)(hu[i] >> 16));
                f0 = gelu_f((f0 - mu)*rs);
                f1 = gelu_f((f1 - mu)*rs);
                pk[i] = (unsigned int)f2h(f0) | ((unsigned int)f2h(f1) << 16);
            }
        } else {
            const float* xr = xs + ci*65;
            #pragma unroll
            for (int i = 0; i < 8; ++i){
                float v[2];
                #pragma unroll
                for (int q = 0; q < 2; ++q){
                    int n = n0 + nq*16 + i*2 + q;
                    float src = (n + 0.5f)*0.015625f - 0.5f;
                    src = fminf(fmaxf(src, 0.0f), 63.0f);
                    int i0 = (int)src;
                    int i1 = (i0 + 1 > 63) ? 63 : (i0 + 1);
                    float wt = src - (float)i0;
                    v[q] = xr[i0] + wt*(xr[i1] - xr[i0]);
                }
                pk[i] = (unsigned int)f2h(v[0]) | ((unsigned int)f2h(v[1]) << 16);
            }
        }
        unsigned int base = (unsigned int)ci*128 + (unsigned int)nq*32;
        unsigned int sw = (unsigned int)((ci & 7) << 4);
        *(uint4*)((char*)xl1 + ((base +  0) ^ sw)) = make_uint4(pk[0],pk[1],pk[2],pk[3]);
        *(uint4*)((char*)xl1 + ((base + 16) ^ sw)) = make_uint4(pk[4],pk[5],pk[6],pk[7]);
        __syncthreads();

        {   // transpose LDS1 [ci][n] -> LDS2 [n][ci] (both swizzled)
            int n = t & 63, coq = t >> 6;
            unsigned int opk[8];
            #pragma unroll
            for (int i = 0; i < 8; ++i){
                int r0 = coq*16 + 2*i, r1 = r0 + 1;
                unsigned int a0 = ((unsigned int)r0*128 + (unsigned int)n*2)
                                  ^ (unsigned int)((r0 & 7) << 4);
                unsigned int a1 = ((unsigned int)r1*128 + (unsigned int)n*2)
                                  ^ (unsigned int)((r1 & 7) << 4);
                unsigned short v0 = *(const unsigned short*)((const char*)xl1 + a0);
                unsigned short v1 = *(const unsigned short*)((const char*)xl1 + a1);
                opk[i] = (unsigned int)v0 | ((unsigned int)v1 << 16);
            }
            unsigned int b0 = (unsigned int)n*128 + (unsigned int)coq*32;
            unsigned int swn = (unsigned int)((n & 7) << 4);
            *(uint4*)((char*)xl2 + ((b0 +  0) ^ swn)) = make_uint4(opk[0],opk[1],opk[2],opk[3]);
            *(uint4*)((char*)xl2 + ((b0 + 16) ^ swn)) = make_uint4(opk[4],opk[5],opk[6],opk[7]);
        }
        __syncthreads();

        // MFMA: wave w owns n rows [w*16, w*16+16) of this 64-tile
        int nl = w*16 + lrow;
        unsigned int swa = (unsigned int)((nl & 7) << 4);
        half8 Af[4];
        Af[0] = *(const half8*)((const char*)xl2 + (((unsigned int)nl*128 +  0 + g*16) ^ swa));
        Af[1] = *(const half8*)((const char*)xl2 + (((unsigned int)nl*128 + 64 + g*16) ^ swa));
        {
            const unsigned short* tb = tabT + (size_t)(n0 + nl)*64 + g*8;
            Af[2] = *(const half8*)(tb);
            Af[3] = *(const half8*)(tb + 32);
        }
        fx4 acc[4];
        #pragma unroll
        for (int i = 0; i < 4; ++i) acc[i] = (fx4){0.f,0.f,0.f,0.f};
        #pragma unroll
        for (int ks = 0; ks < 4; ++ks)
            #pragma unroll
            for (int cot = 0; cot < 4; ++cot)
                acc[cot] = __builtin_amdgcn_mfma_f32_16x16x32_f16(Af[ks], Bv[cot][ks], acc[cot], 0, 0, 0);

        // epilogue: h = acc + bias; packed uint2 store; stats accumulate
        #pragma unroll
        for (int cot = 0; cot < 4; ++cot){
            int co = cot*16 + lrow;
            unsigned short* hr = xh + ((size_t)(b*64+co))*4096;
            float h0 = acc[cot][0] + pb[cot];
            float h1 = acc[cot][1] + pb[cot];
            float h2 = acc[cot][2] + pb[cot];
            float h3 = acc[cot][3] + pb[cot];
            uint2 pk2;
            pk2.x = (unsigned int)f2h(h0) | ((unsigned int)f2h(h1) << 16);
            pk2.y = (unsigned int)f2h(h2) | ((unsigned int)f2h(h3) << 16);
            *(uint2*)(hr + n0 + w*16 + g*4) = pk2;
            sS[cot] += (h0 + h1) + (h2 + h3);
            float q = h0*h0;
            q = fmaf(h1, h1, q); q = fmaf(h2, h2, q); q = fmaf(h3, h3, q);
            sQ[cot] += q;
        }
        if (MODE == 1 && it < 3){ cA = nA; cB = nB; }
    }
    #pragma unroll
    for (int cot = 0; cot < 4; ++cot){
        float s = sS[cot], q = sQ[cot];
        s += __shfl_xor(s, 16); q += __shfl_xor(q, 16);
        s += __shfl_xor(s, 32); q += __shfl_xor(q, 32);
        if (g == 0){
            sred[0][w][cot*16 + lrow] = s;
            sred[1][w][cot*16 + lrow] = q;
        }
    }
    __syncthreads();
    if (t < 64){
        float S = 0.f, Q = 0.f;
        #pragma unroll
        for (int ww = 0; ww < 4; ++ww){ S += sred[0][ww][t]; Q += sred[1][ww][t]; }
        atomicAdd(statsOut + (size_t)(b*64+t)*2,     S);
        atomicAdd(statsOut + (size_t)(b*64+t)*2 + 1, Q);
    }
}

// ---------------- fused norm+gelu+projection head (LDS2 transpose, vector B) -----
// grid (128 b, 16 ng of 256 n), 4 iters per block.
__global__ __launch_bounds__(256) void k_proj2(
        const unsigned short* __restrict__ xhp, const float* __restrict__ statsIn,
        const unsigned short* __restrict__ w1h, const float* __restrict__ b1,
        const float* __restrict__ w2, const float* __restrict__ b2,
        float* __restrict__ out)
{
    int b = blockIdx.x, ng = blockIdx.y;
    int t = threadIdx.x, w = t >> 6, lane = t & 63;
    int lrow = lane & 15, g = lane >> 4;
    int o2h = w & 1, nhalf = w >> 1;
    __shared__ __align__(16) unsigned short xl1[4096];
    __shared__ __align__(16) unsigned short xl2[4096];
    __shared__ float sred[2][2][2][2][16];   // [buf][nhalf][nt][o2h][lrow]

    int ci = t >> 2, nq = t & 3;
    float2 sr = *(const float2*)(statsIn + (size_t)(b*64+ci)*2);
    float mu = sr.x * (1.f/4096.f);
    float var = fmaf(sr.y, 1.f/4096.f, -mu*mu);
    float rs = rsqrtf(var + 1e-5f);
    const unsigned short* hrow = xhp + ((size_t)(b*64+ci))*4096 + ng*256 + nq*16;

    half8 A[4][2];
    #pragma unroll
    for (int ot = 0; ot < 4; ++ot)
        #pragma unroll
        for (int ks = 0; ks < 2; ++ks)
            A[ot][ks] = *(const half8*)(w1h + (size_t)(o2h*64 + ot*16 + lrow)*64 + ks*32 + g*8);
    float bb[16], wv[16];
    #pragma unroll
    for (int ot = 0; ot < 4; ++ot)
        #pragma unroll
        for (int j = 0; j < 4; ++j){
            int o2 = o2h*64 + ot*16 + g*4 + j;
            bb[ot*4+j] = b1[o2];
            wv[ot*4+j] = w2[o2];
        }
    float bias2 = b2[0];

    uint4 cA = *(const uint4*)(hrow);
    uint4 cB = *(const uint4*)(hrow + 8);
    for (int it = 0; it < 4; ++it){
        uint4 nA, nB;
        if (it < 3){
            nA = *(const uint4*)(hrow + (it+1)*64);
            nB = *(const uint4*)(hrow + (it+1)*64 + 8);
        }
        unsigned int pk[8];
        {
            unsigned int hu[8] = {cA.x,cA.y,cA.z,cA.w,cB.x,cB.y,cB.z,cB.w};
            #pragma unroll
            for (int i = 0; i < 8; ++i){
                float f0 = h2f((unsigned short)(hu[i] & 0xFFFFu));
                float f1 = h2f((unsigned short)(hu[i] >> 16));
                f0 = gelu_f((f0 - mu)*rs);
                f1 = gelu_f((f1 - mu)*rs);
                pk[i] = (unsigned int)f2h(f0) | ((unsigned int)f2h(f1) << 16);
            }
        }
        unsigned int base = (unsigned int)ci*128 + (unsigned int)nq*32;
        unsigned int sw = (unsigned int)((ci & 7) << 4);
        *(uint4*)((char*)xl1 + ((base +  0) ^ sw)) = make_uint4(pk[0],pk[1],pk[2],pk[3]);
        *(uint4*)((char*)xl1 + ((base + 16) ^ sw)) = make_uint4(pk[4],pk[5],pk[6],pk[7]);
        __syncthreads();

        {   // transpose LDS1 -> LDS2
            int n = t & 63, coq = t >> 6;
            unsigned int opk[8];
            #pragma unroll
            for (int i = 0; i < 8; ++i){
                int r0 = coq*16 + 2*i, r1 = r0 + 1;
                unsigned int a0 = ((unsigned int)r0*128 + (unsigned int)n*2)
                                  ^ (unsigned int)((r0 & 7) << 4);
                unsigned int a1 = ((unsigned int)r1*128 + (unsigned int)n*2)
                                  ^ (unsigned int)((r1 & 7) << 4);
                unsigned short v0 = *(const unsigned short*)((const char*)xl1 + a0);
                unsigned short v1 = *(const unsigned short*)((const char*)xl1 + a1);
                opk[i] = (unsigned int)v0 | ((unsigned int)v1 << 16);
            }
            unsigned int b0 = (unsigned int)n*128 + (unsigned int)coq*32;
            unsigned int swn = (unsigned int)((n & 7) << 4);
            *(uint4*)((char*)xl2 + ((b0 +  0) ^ swn)) = make_uint4(opk[0],opk[1],opk[2],opk[3]);
            *(uint4*)((char*)xl2 + ((b0 + 16) ^ swn)) = make_uint4(opk[4],opk[5],opk[6],opk[7]);
        }
        __syncthreads();

        // out-store for previous iter
        if (it > 0 && t < 64){
            int nh = t >> 5, rem = t & 31, ntf = rem >> 4, cl = rem & 15;
            out[(size_t)b*4096 + ng*256 + (it-1)*64 + t] =
                sred[(it-1)&1][nh][ntf][0][cl] + sred[(it-1)&1][nh][ntf][1][cl] + bias2;
        }

        // MFMA: vector B-frags from LDS2
        #pragma unroll
        for (int nt = 0; nt < 2; ++nt){
            int n_l = nhalf*32 + nt*16 + lrow;
            unsigned int swa = (unsigned int)((n_l & 7) << 4);
            half8 Bf[2];
            Bf[0] = *(const half8*)((const char*)xl2 + (((unsigned int)n_l*128 +  0 + g*16) ^ swa));
            Bf[1] = *(const half8*)((const char*)xl2 + (((unsigned int)n_l*128 + 64 + g*16) ^ swa));
            fx4 acc[4];
            #pragma unroll
            for (int i = 0; i < 4; ++i) acc[i] = (fx4){0.f,0.f,0.f,0.f};
            #pragma unroll
            for (int ks = 0; ks < 2; ++ks)
                #pragma unroll
                for (int ot = 0; ot < 4; ++ot)
                    acc[ot] = __builtin_amdgcn_mfma_f32_16x16x32_f16(A[ot][ks], Bf[ks], acc[ot], 0, 0, 0);
            float p = 0.f;
            #pragma unroll
            for (int ot = 0; ot < 4; ++ot)
                #pragma unroll
                for (int j = 0; j < 4; ++j)
                    p = fmaf(wv[ot*4+j], gelu_f(acc[ot][j] + bb[ot*4+j]), p);
            p += __shfl_xor(p, 16); p += __shfl_xor(p, 32);
            if (lane < 16) sred[it & 1][nhalf][nt][o2h][lane] = p;
        }
        if (it < 3){ cA = nA; cB = nB; }
    }
    __syncthreads();
    if (t < 64){
        int nh = t >> 5, rem = t & 31, ntf = rem >> 4, cl = rem & 15;
        out[(size_t)b*4096 + ng*256 + 3*64 + t] =
            sred[1][nh][ntf][0][cl] + sred[1][nh][ntf][1][cl] + bias2;
    }
}

// ---------------- launch ----------------
extern "C" void kernel_launch(void* const* d_in, const int* in_sizes, int n_in,
                              void* d_out, int out_size, void* d_ws, size_t ws_size,
                              hipStream_t stream) {
    (void)in_sizes; (void)n_in; (void)out_size; (void)ws_size;
    const float* z      = (const float*)d_in[0];
    const float* instp  = (const float*)d_in[1];
    const float* lift_w = (const float*)d_in[2];
    const float* lift_b = (const float*)d_in[3];
    const float* iw1    = (const float*)d_in[4];
    const float* ib1    = (const float*)d_in[5];
    const float* iw2    = (const float*)d_in[6];
    const float* ib2    = (const float*)d_in[7];
    const float* specw  = (const float*)d_in[8];
    const float* pww    = (const float*)d_in[9];
    const float* pwb    = (const float*)d_in[10];
    const float* pj1w   = (const float*)d_in[11];
    const float* pj1b   = (const float*)d_in[12];
    const float* pj2w   = (const float*)d_in[13];
    const float* pj2b   = (const float*)d_in[14];

    float* ws = (float*)d_ws;
    unsigned short* xh    = (unsigned short*)(ws + OFF_XH);
    unsigned short* tabB  = (unsigned short*)(ws + OFF_TABB);
    unsigned short* tabT  = (unsigned short*)(ws + OFF_TABT);
    unsigned short* mah   = (unsigned short*)(ws + OFF_MAH);
    unsigned short* pwwh  = (unsigned short*)(ws + OFF_PWWH);
    unsigned short* w1h   = (unsigned short*)(ws + OFF_W1H);
    float* cond   = ws + OFF_COND;
    float* dftp   = ws + OFF_DFTP;
    float* x0     = ws + OFF_X0;
    float* sbuf[2] = { ws + OFF_STATS, ws + OFF_STATS2 };
    float* out    = (float*)d_out;

    k_tab  <<<dim3(1024),  dim3(256), 0, stream>>>(tabB, tabT, pww, pwwh, pj1w, w1h);
    k_cond <<<dim3(128),   dim3(64),  0, stream>>>(instp, iw1, ib1, iw2, ib2, cond);
    k_liftc<<<dim3(128,4), dim3(256), 0, stream>>>(z, lift_w, lift_b, cond, x0);

    for (int l = 0; l < 4; ++l){
        float* sIn  = sbuf[l & 1];
        float* sOut = sbuf[(l + 1) & 1];
        if (l == 0)
            k_prep<2><<<dim3(128,8), dim3(256), 0, stream>>>(xh, sIn, tabB, x0, dftp);
        else
            k_prep<1><<<dim3(128,8), dim3(256), 0, stream>>>(xh, sIn, tabB, x0, dftp);
        k_mix<<<dim3(128,4), dim3(256), 0, stream>>>(dftp, specw, mah, sOut, l);
        if (l == 0)
            k_pass3<2><<<dim3(128,16), dim3(256), 0, stream>>>(xh, sIn, x0, tabT, pwwh, pwb, mah, xh, sOut, l);
        else
            k_pass3<1><<<dim3(128,16), dim3(256), 0, stream>>>(xh, sIn, x0, tabT, pwwh, pwb, mah, xh, sOut, l);
    }
    k_proj2<<<dim3(128,16), dim3(256), 0, stream>>>(xh, sbuf[0], w1h, pj1b, pj2w, pj2b, out);
}